// Round 1
// 11083.422 us; speedup vs baseline: 1.1650x; 1.1650x over previous
//
#include <hip/hip_runtime.h>
#include <hip/hip_bf16.h>
#include <stdint.h>

// Problem dims
#define BB 64
#define TT 512
#define EE 512
#define HH 1024
#define KTOT 1536          // E + H
#define CHUNK 8            // h-columns per workgroup (128 WGs per direction)
#define NKI 12             // K windows of 32 per wave (4 waves x 12 x 32 = 1536)
#define NKX 4              // x windows per wave (K 0..511)
#define NKH 8              // h windows per wave (K 512..1535)
#define HPD 3              // h-load register prefetch depth
#define NWGD 128           // workgroups per direction
#define NWG  256           // total workgroups

typedef __bf16 bf16_t;
typedef __bf16 bf16x8 __attribute__((ext_vector_type(8)));
typedef float  f32x4  __attribute__((ext_vector_type(4)));
typedef unsigned int u32x4 __attribute__((ext_vector_type(4)));
typedef unsigned long long u64;

static_assert(sizeof(bf16x8) == 16, "bf16x8 must be 16B");

__device__ __forceinline__ f32x4 mfma_16x16x32_bf16(bf16x8 a, bf16x8 b, f32x4 c) {
    return __builtin_amdgcn_mfma_f32_16x16x32_bf16(a, b, c, 0, 0, 0);
}

// Split 8 consecutive f32 (two float4 loads) into hi/lo bf16x8 fragments.
__device__ __forceinline__ void split8(const float* __restrict__ src,
                                       bf16x8& hi, bf16x8& lo) {
    const f32x4 a = *(const f32x4*)src;
    const f32x4 b = *(const f32x4*)(src + 4);
    #pragma unroll
    for (int j = 0; j < 4; ++j) {
        const bf16_t h0 = (bf16_t)a[j];
        hi[j] = h0;  lo[j] = (bf16_t)(a[j] - (float)h0);
        const bf16_t h1 = (bf16_t)b[j];
        hi[4 + j] = h1;  lo[4 + j] = (bf16_t)(b[j] - (float)h1);
    }
}

// One-time counter barrier (init fence only; per-step sync uses flags below).
__device__ __forceinline__ void ctr_barrier(unsigned int* slot, unsigned int target) {
    __syncthreads();                  // drains each wave's vmem
    if (threadIdx.x == 0) {
        __hip_atomic_fetch_add(slot, 1u, __ATOMIC_RELAXED, __HIP_MEMORY_SCOPE_AGENT);
        int guard = 0;
        while (__hip_atomic_load(slot, __ATOMIC_RELAXED, __HIP_MEMORY_SCOPE_AGENT) < target) {
            __builtin_amdgcn_s_sleep(2);
            if (++guard > (1 << 22)) break;   // fail visibly, don't hang the queue
        }
    }
    __syncthreads();
}

// Persistent bidirectional LSTM, FP32 I/O, split-bf16 MFMA (acc = Ahi*Bhi +
// Ahi*Blo + Alo*Bhi in f32). grid = 256 x 256; blocks 0..127 fwd, 128..255 bwd.
// Per step:
//   [pre-wait]  x loads (depth-4 regs) + all x-window MFMAs   (no h dependency)
//   [wait]      wave0 polls 128 per-WG flags (u64/lane + __all), sync releases
//   [post-wait] h windows: depth-3 register pipeline of sc1 u64 loads,
//               v_perm unpack, MFMAs; LDS cross-wave reduce; epilogue;
//               h store (sc1) -> syncthreads (drain) -> flag store -> out adds
// Arithmetic order identical to the previous kernel (ki = 0..3 x, 4..11 h,
// products hi*bh, hi*bl, lo*bh per window) => bit-identical results.
__global__ __launch_bounds__(256, 1)
void lstm_persistent(const float* __restrict__ x,
                     const float* __restrict__ h0,
                     const float* __restrict__ c0,
                     const float* __restrict__ Ufw, const float* __restrict__ Ufb,
                     const float* __restrict__ Wfw, const float* __restrict__ Wfb,
                     const float* __restrict__ Ubw, const float* __restrict__ Ubb,
                     const float* __restrict__ Wbw, const float* __restrict__ Wbb,
                     bf16_t* __restrict__ xhi,    // [B][T][E] bf16 plane
                     bf16_t* __restrict__ xlo,    // [B][T][E] bf16 plane
                     unsigned int* __restrict__ hbuf, // [parity2][dir2][B][H] u32(hi,lo)
                     float*  __restrict__ out,    // [B][T][H] f32 + [2][B][H] tail
                     unsigned int* __restrict__ ctr) // [0]=init ctr, [16..271]=flags
{
    __shared__ f32x4 red[4][8][64];   // [wave][tile][lane] partials, 32 KiB

    const int wg   = blockIdx.x;
    const int dir  = wg >> 7;
    const int cb   = (wg & 127) * CHUNK;
    const int tid  = threadIdx.x;
    const int wave = tid >> 6;
    const int lane = tid & 63;
    const int l16  = lane & 15;
    const int quad = lane >> 4;
    const int wg127 = wg & 127;

    unsigned int* flags = ctr + 16 + dir * NWGD;   // 128 u32 per direction

    const float* Uw = dir ? Ubw : Ufw;
    const float* Ww = dir ? Wbw : Wfw;
    const float* Ub = dir ? Ubb : Ufb;
    const float* Wb = dir ? Wbb : Wfb;

    // ================= pre-phase (before the one-time fence) =================
    const int gid = wg * 256 + tid;          // 0 .. 65535
    // (A) split x into hi/lo planes (plain stores; flushed by the one fence)
    {
        const int NG = BB * TT * EE / 8;
        for (int g = gid; g < NG; g += NWG * 256) {
            bf16x8 hi, lo;
            split8(x + (size_t)g * 8, hi, lo);
            ((bf16x8*)xhi)[g] = hi;
            ((bf16x8*)xlo)[g] = lo;
        }
    }
    // (B) zero out[0 : B*T*H)  (atomicAdds later bypass L2 -> must be flushed)
    {
        const int NZ = BB * TT * HH / 4;
        const f32x4 z = {0.f, 0.f, 0.f, 0.f};
        for (int g = gid; g < NZ; g += NWG * 256) ((f32x4*)out)[g] = z;
    }
    // (C) tail passthrough: out[BTH : BTH+BH) = h0, then c0
    {
        float* tail = out + (size_t)BB * TT * HH;
        const int NT4 = BB * HH / 4;
        for (int g = gid; g < NT4; g += NWG * 256)
            ((f32x4*)tail)[g] = ((const f32x4*)h0)[g];
        for (int g = gid; g < NT4; g += NWG * 256)
            ((f32x4*)(tail + BB * HH))[g] = ((const f32x4*)c0)[g];
    }
    // (D) stage packed split h0 (own columns) into parity-1 buffer (sc1 stores)
    {
        unsigned int* p1 = hbuf + ((size_t)(1 * 2 + dir)) * (BB * HH);
        for (int i = tid; i < BB * CHUNK; i += 256) {
            const int b = i >> 3, col = cb + (i & 7);
            const float v = h0[b * HH + col];
            const bf16_t vh = (bf16_t)v;
            const bf16_t vl = (bf16_t)(v - (float)vh);
            const unsigned int pk =
                (unsigned int)__builtin_bit_cast(unsigned short, vh) |
                ((unsigned int)__builtin_bit_cast(unsigned short, vl) << 16);
            __hip_atomic_store(&p1[b * HH + col], pk, __ATOMIC_RELAXED,
                               __HIP_MEMORY_SCOPE_AGENT);
        }
    }

    // ---- preload [U;W] hi/lo fragments (A operand) into registers ----
    bf16x8 whi[2][NKI], wlo[2][NKI];
    #pragma unroll
    for (int mt = 0; mt < 2; ++mt) {
        const int r    = mt * 16 + l16;                  // local row 0..31
        const int grow = (r & 3) * HH + (cb + (r >> 2)); // gate*H + hcol
        const float* urow = Uw + (size_t)grow * EE;
        const float* wrow = Ww + (size_t)grow * HH;
        #pragma unroll
        for (int ki = 0; ki < NKI; ++ki) {
            const int ws0 = (ki * 4 + wave) * 32;        // interleaved mapping
            const float* src = (ws0 < EE ? urow + ws0 : wrow + (ws0 - EE)) + quad * 8;
            split8(src, whi[mt][ki], wlo[mt][ki]);
        }
    }

    // Epilogue ownership: wave w finalizes nt == w -> batch b = wave*16 + l16,
    // h-col = cb + mt*4 + quad, gates f,i,g,o in regs 0..3.
    const int bown = wave * 16 + l16;
    float biasv[2][4];
    float cst[2];
    #pragma unroll
    for (int mt = 0; mt < 2; ++mt) {
        const int hcol = cb + mt * 4 + quad;
        #pragma unroll
        for (int g = 0; g < 4; ++g)
            biasv[mt][g] = Ub[g * HH + hcol] + Wb[g * HH + hcol];
        cst[mt] = c0[bown * HH + hcol];
    }

    // ONE-TIME fence: flush pre-phase plain stores (x planes, out zeros, tail)
    // to the coherence point, then full-grid barrier.
    __threadfence();
    ctr_barrier(ctr + 0, NWG);

    const f32x4 vzero = {0.f, 0.f, 0.f, 0.f};

    for (int t = 0; t < TT; ++t) {
        const int tx = dir ? (TT - 1 - t) : t;
        const unsigned int* hb32 =
            hbuf + ((size_t)((((t + 1) & 1)) * 2 + dir)) * (BB * HH);

        const bf16_t *xrh[4], *xrl[4];
        const unsigned int* hr32[4];
        #pragma unroll
        for (int nt = 0; nt < 4; ++nt) {
            const int b = nt * 16 + l16;     // B-operand: n = lane&15
            const size_t xoff = ((size_t)b * TT + tx) * EE;
            xrh[nt] = xhi + xoff;  xrl[nt] = xlo + xoff;
            hr32[nt] = hb32 + (size_t)b * HH;
        }

        // ================= x-phase: independent of h_{t-1} =================
        f32x4 acc[2][4];
        #pragma unroll
        for (int mt = 0; mt < 2; ++mt)
            #pragma unroll
            for (int nt = 0; nt < 4; ++nt) acc[mt][nt] = vzero;

        bf16x8 xbh[NKX][4], xbl[NKX][4];
        #pragma unroll
        for (int kx = 0; kx < NKX; ++kx) {
            const int off = (kx * 4 + wave) * 32 + quad * 8;
            #pragma unroll
            for (int nt = 0; nt < 4; ++nt) {
                xbh[kx][nt] = *(const bf16x8*)(xrh[nt] + off);
                xbl[kx][nt] = *(const bf16x8*)(xrl[nt] + off);
            }
        }
        #pragma unroll
        for (int kx = 0; kx < NKX; ++kx)
            #pragma unroll
            for (int mt = 0; mt < 2; ++mt)
                #pragma unroll
                for (int nt = 0; nt < 4; ++nt) {
                    acc[mt][nt] = mfma_16x16x32_bf16(whi[mt][kx], xbh[kx][nt], acc[mt][nt]);
                    acc[mt][nt] = mfma_16x16x32_bf16(whi[mt][kx], xbl[kx][nt], acc[mt][nt]);
                    acc[mt][nt] = mfma_16x16x32_bf16(wlo[mt][kx], xbh[kx][nt], acc[mt][nt]);
                }

        // ============ wait for h_{t-1}: distributed per-WG flags ============
        // wave 0 polls all 128 flags of its direction (2 per lane via one u64
        // relaxed agent load); __syncthreads releases the other waves.
        if (t > 0) {
            if (wave == 0) {
                const u64* f64 = (const u64*)flags;
                const unsigned int tgt = (unsigned int)t;
                int guard = 0;
                for (;;) {
                    const u64 v = __hip_atomic_load(f64 + lane, __ATOMIC_RELAXED,
                                                    __HIP_MEMORY_SCOPE_AGENT);
                    const int ok = ((unsigned int)v >= tgt) &&
                                   ((unsigned int)(v >> 32) >= tgt);
                    if (__all(ok)) break;
                    __builtin_amdgcn_s_sleep(1);
                    if (++guard > (1 << 22)) break;   // fail visibly, no hang
                }
            }
            __syncthreads();
        }

        // ======= h-phase: depth-HPD pipelined sc1 loads, v_perm unpack =======
        u64 hbq[HPD][4][4];                  // raw packed payload, 96 VGPRs
        #pragma unroll
        for (int p = 0; p < HPD; ++p) {
            const int off = (p * 4 + wave) * 32 + quad * 8;
            #pragma unroll
            for (int nt = 0; nt < 4; ++nt) {
                const u64* p64 = (const u64*)(hr32[nt] + off);
                #pragma unroll
                for (int j = 0; j < 4; ++j)
                    hbq[p][nt][j] = __hip_atomic_load(p64 + j, __ATOMIC_RELAXED,
                                                      __HIP_MEMORY_SCOPE_AGENT);
            }
        }
        #pragma unroll
        for (int kh = 0; kh < NKH; ++kh) {
            const int s = kh % HPD;          // compile-time after unroll
            bf16x8 bh[4], bl[4];
            #pragma unroll
            for (int nt = 0; nt < 4; ++nt) {
                u32x4 hw, lw;
                #pragma unroll
                for (int j = 0; j < 4; ++j) {
                    const u64 v = hbq[s][nt][j];
                    const unsigned int lo = (unsigned int)v;
                    const unsigned int hi = (unsigned int)(v >> 32);
                    hw[j] = __builtin_amdgcn_perm(hi, lo, 0x05040100u); // hi16 parts
                    lw[j] = __builtin_amdgcn_perm(hi, lo, 0x07060302u); // lo16 parts
                }
                bh[nt] = __builtin_bit_cast(bf16x8, hw);
                bl[nt] = __builtin_bit_cast(bf16x8, lw);
            }
            if (kh + HPD < NKH) {            // refill the slot just consumed
                const int off = ((kh + HPD) * 4 + wave) * 32 + quad * 8;
                #pragma unroll
                for (int nt = 0; nt < 4; ++nt) {
                    const u64* p64 = (const u64*)(hr32[nt] + off);
                    #pragma unroll
                    for (int j = 0; j < 4; ++j)
                        hbq[s][nt][j] = __hip_atomic_load(p64 + j, __ATOMIC_RELAXED,
                                                          __HIP_MEMORY_SCOPE_AGENT);
                }
            }
            const int ki = NKX + kh;
            #pragma unroll
            for (int mt = 0; mt < 2; ++mt)
                #pragma unroll
                for (int nt = 0; nt < 4; ++nt) {
                    acc[mt][nt] = mfma_16x16x32_bf16(whi[mt][ki], bh[nt], acc[mt][nt]);
                    acc[mt][nt] = mfma_16x16x32_bf16(whi[mt][ki], bl[nt], acc[mt][nt]);
                    acc[mt][nt] = mfma_16x16x32_bf16(wlo[mt][ki], bh[nt], acc[mt][nt]);
                }
        }

        // ================= cross-wave K reduction through LDS =================
        #pragma unroll
        for (int mt = 0; mt < 2; ++mt)
            #pragma unroll
            for (int nt = 0; nt < 4; ++nt)
                red[wave][mt * 4 + nt][lane] = acc[mt][nt];
        __syncthreads();

        unsigned int* hn32 = hbuf + ((size_t)((t & 1) * 2 + dir)) * (BB * HH);
        float hvout[2];
        #pragma unroll
        for (int mt = 0; mt < 2; ++mt) {
            const int tI = mt * 4 + wave;    // this wave finalizes nt == wave
            f32x4 s = red[0][tI][lane];
            #pragma unroll
            for (int w2 = 1; w2 < 4; ++w2) s += red[w2][tI][lane];
            const float fg = s[0] + biasv[mt][0];
            const float ig = s[1] + biasv[mt][1];
            const float gg = s[2] + biasv[mt][2];
            const float og = s[3] + biasv[mt][3];   // o gate used RAW (ref quirk)
            const float sf = 1.f / (1.f + __expf(-fg));
            const float si = 1.f / (1.f + __expf(-ig));
            float cn = cst[mt] * sf + si * tanhf(gg);
            cn = fminf(600.f, fmaxf(-600.f, cn));   // inert when correct
            cst[mt] = cn;
            float hv = og * tanhf(cn);
            hv = fminf(448.f, fmaxf(-448.f, hv));   // inert when correct
            const int hcol = cb + mt * 4 + quad;
            const bf16_t vh = (bf16_t)hv;
            const bf16_t vl = (bf16_t)(hv - (float)vh);
            const unsigned int pk =
                (unsigned int)__builtin_bit_cast(unsigned short, vh) |
                ((unsigned int)__builtin_bit_cast(unsigned short, vl) << 16);
            __hip_atomic_store(&hn32[(size_t)bown * HH + hcol], pk,
                               __ATOMIC_RELAXED, __HIP_MEMORY_SCOPE_AGENT);
            hvout[mt] = hv;
        }

        // Publish: syncthreads' implicit vmcnt(0) drains all waves' h stores
        // to the coherence point, then one flag store. out atomicAdds go AFTER
        // the flag (no ordering needed; off the critical path).
        __syncthreads();
        if (tid == 0)
            __hip_atomic_store(&flags[wg127], (unsigned int)(t + 1),
                               __ATOMIC_RELAXED, __HIP_MEMORY_SCOPE_AGENT);
        #pragma unroll
        for (int mt = 0; mt < 2; ++mt)
            atomicAdd(&out[((size_t)bown * TT + tx) * HH + (cb + mt * 4 + quad)],
                      hvout[mt]);
    }
}

// Diagnostic sentinel: fills out with a constant so failures are attributable.
__global__ void sentinel_kernel(float* __restrict__ out, float v, size_t n)
{
    const size_t i = (size_t)blockIdx.x * blockDim.x + threadIdx.x;
    if (i < n) out[i] = v;
}

extern "C" void kernel_launch(void* const* d_in, const int* in_sizes, int n_in,
                              void* d_out, int out_size, void* d_ws, size_t ws_size,
                              hipStream_t stream)
{
    const float* x   = (const float*)d_in[0];
    const float* h0  = (const float*)d_in[1];
    const float* c0  = (const float*)d_in[2];
    const float* Ufw = (const float*)d_in[3];
    const float* Ufb = (const float*)d_in[4];
    const float* Wfw = (const float*)d_in[5];
    const float* Wfb = (const float*)d_in[6];
    const float* Ubw = (const float*)d_in[7];
    const float* Ubb = (const float*)d_in[8];
    const float* Wbw = (const float*)d_in[9];
    const float* Wbb = (const float*)d_in[10];

    const size_t n_out = (size_t)out_size;

    // ws layout: [ctr 8KB][xhi 32MB][xlo 32MB][hbuf 2MB u32-packed]
    const size_t CTRB = 8192;
    const size_t XPB  = (size_t)BB * TT * EE * sizeof(bf16_t);        // 32 MiB
    const size_t HBUF = (size_t)2 * 2 * BB * HH * sizeof(unsigned int); // 2 MiB
    if (ws_size < CTRB + 2 * XPB + HBUF) {
        hipLaunchKernelGGL(sentinel_kernel, dim3((unsigned)((n_out + 255) / 256)),
                           dim3(256), 0, stream, (float*)d_out, 1000.0f, n_out);
        return;
    }

    uint8_t* ws = (uint8_t*)d_ws;
    unsigned int* ctr = (unsigned int*)ws;
    bf16_t* xhi  = (bf16_t*)(ws + CTRB);
    bf16_t* xlo  = (bf16_t*)(ws + CTRB + XPB);
    unsigned int* hbuf = (unsigned int*)(ws + CTRB + 2 * XPB);
    float*  out  = (float*)d_out;

    hipMemsetAsync(ctr, 0, CTRB, stream);

    hipLaunchKernelGGL(lstm_persistent, dim3(NWG), dim3(256), 0, stream,
                       x, h0, c0, Ufw, Ufb, Wfw, Wfb, Ubw, Ubb, Wbw, Wbb,
                       xhi, xlo, hbuf, out, ctr);
}

// Round 2
// 7003.892 us; speedup vs baseline: 1.8435x; 1.5825x over previous
//
#include <hip/hip_runtime.h>
#include <hip/hip_bf16.h>
#include <stdint.h>

// Problem dims
#define BB 64
#define TT 512
#define EE 512
#define HH 1024
#define CHUNK 8            // h-columns per workgroup (128 WGs per direction)
#define NKI 12             // K windows of 32 per wave (4 waves x 12 x 32 = 1536)
#define NKX 4              // x windows per wave (K 0..511)
#define NKH 8              // h windows per wave (K 512..1535)
#define NWGD 128           // workgroups per direction
#define NWG  256           // total workgroups

// ctr u32 offsets
#define CTR_INIT  0        // one-time init barrier counter
#define CTR_FLAG  16       // 256 per-WG step flags (128 per dir)
#define CTR_ELECT 512      // 16 election counters [xcd][dir]
#define CTR_XBAR  1024     // 16*512 per-step per-(xcd,dir) barrier slots
#define CTRB      65536    // bytes

#define HFRAGS 8192              // stage frags per (xcd,dir) plane: 128 k8 * 64 b
#define PLANE_BF16 (HFRAGS * 8)  // bf16 units per plane

typedef __bf16 bf16_t;
typedef __bf16 bf16x8 __attribute__((ext_vector_type(8)));
typedef float  f32x4  __attribute__((ext_vector_type(4)));
typedef unsigned int u32x4 __attribute__((ext_vector_type(4)));
typedef unsigned long long u64;

static_assert(sizeof(bf16x8) == 16, "bf16x8 must be 16B");

__device__ __forceinline__ f32x4 mfma_16x16x32_bf16(bf16x8 a, bf16x8 b, f32x4 c) {
    return __builtin_amdgcn_mfma_f32_16x16x32_bf16(a, b, c, 0, 0, 0);
}

__device__ __forceinline__ unsigned int lo32(u64 v) { return (unsigned int)v; }
__device__ __forceinline__ unsigned int hi32(u64 v) { return (unsigned int)(v >> 32); }

// L1-bypassing (sc0) 16B load: hits the XCD-local L2 where the stage copier's
// plain stores landed. Compiler doesn't track this vmem op -> consumers must
// s_waitcnt vmcnt(0) + sched_barrier(0) before use (rule #18). Extra untracked
// loads only make compiler-inserted vmcnt waits MORE conservative (FIFO count).
template<int OFF>
__device__ __forceinline__ bf16x8 ld_sc0(const bf16_t* p) {
    bf16x8 d;
    asm volatile("global_load_dwordx4 %0, %1, off offset:%2 sc0"
                 : "=v"(d) : "v"(p), "n"(OFF));
    return d;
}

// Split 8 consecutive f32 (two float4 loads) into hi/lo bf16x8 fragments.
__device__ __forceinline__ void split8(const float* __restrict__ src,
                                       bf16x8& hi, bf16x8& lo) {
    const f32x4 a = *(const f32x4*)src;
    const f32x4 b = *(const f32x4*)(src + 4);
    #pragma unroll
    for (int j = 0; j < 4; ++j) {
        const bf16_t h0 = (bf16_t)a[j];
        hi[j] = h0;  lo[j] = (bf16_t)(a[j] - (float)h0);
        const bf16_t h1 = (bf16_t)b[j];
        hi[4 + j] = h1;  lo[4 + j] = (bf16_t)(b[j] - (float)h1);
    }
}

// One-time counter barrier (init fence only).
__device__ __forceinline__ void ctr_barrier(unsigned int* slot, unsigned int target) {
    __syncthreads();                  // drains each wave's vmem
    if (threadIdx.x == 0) {
        __hip_atomic_fetch_add(slot, 1u, __ATOMIC_RELAXED, __HIP_MEMORY_SCOPE_AGENT);
        int guard = 0;
        while (__hip_atomic_load(slot, __ATOMIC_RELAXED, __HIP_MEMORY_SCOPE_AGENT) < target) {
            __builtin_amdgcn_s_sleep(2);
            if (++guard > (1 << 22)) break;   // fail visibly, don't hang the queue
        }
    }
    __syncthreads();
}

// Persistent bidirectional LSTM, FP32 I/O, split-bf16 MFMA.
// Per step:
//   x loads (regs) -> flag wait -> per-XCD copy of h (MALL -> local L2, hi/lo
//   planes in fragment order) overlapped with x-MFMAs -> per-(xcd,dir) barrier
//   -> h-phase from L2 via sc0 loads (zero unpack VALU) -> LDS reduce ->
//   epilogue -> h agent-store -> drain -> flag -> out atomics.
// MFMA order identical to previous kernel => bit-identical results.
__global__ __launch_bounds__(256, 1)
void lstm_persistent(const float* __restrict__ x,
                     const float* __restrict__ h0,
                     const float* __restrict__ c0,
                     const float* __restrict__ Ufw, const float* __restrict__ Ufb,
                     const float* __restrict__ Wfw, const float* __restrict__ Wfb,
                     const float* __restrict__ Ubw, const float* __restrict__ Ubb,
                     const float* __restrict__ Wbw, const float* __restrict__ Wbb,
                     bf16_t* __restrict__ xhi,    // [B][T][E] bf16 plane
                     bf16_t* __restrict__ xlo,    // [B][T][E] bf16 plane
                     unsigned int* __restrict__ hbuf, // [parity2][dir2][B][H] u32(hi,lo)
                     bf16_t* __restrict__ stage,  // [xcd8][dir2][plane2][HFRAGS*8] bf16
                     float*  __restrict__ out,    // [B][T][H] f32 + [2][B][H] tail
                     unsigned int* __restrict__ ctr)
{
    __shared__ f32x4 red[4][8][64];   // [wave][tile][lane] partials, 32 KiB
    __shared__ unsigned int s_xcd, s_rank, s_cnt;

    const int wg   = blockIdx.x;
    const int dir  = wg >> 7;
    const int cb   = (wg & 127) * CHUNK;
    const int tid  = threadIdx.x;
    const int wave = tid >> 6;
    const int lane = tid & 63;
    const int l16  = lane & 15;
    const int quad = lane >> 4;
    const int wg127 = wg & 127;

    unsigned int* flags = ctr + CTR_FLAG + dir * NWGD;   // 128 u32 per direction

    const float* Uw = dir ? Ubw : Ufw;
    const float* Ww = dir ? Wbw : Wfw;
    const float* Ub = dir ? Ubb : Ufb;
    const float* Wb = dir ? Wbb : Wfb;

    // ---- XCD discovery + per-(xcd,dir) rank election ----
    if (tid == 0) {
        unsigned int xcc;
        asm volatile("s_getreg_b32 %0, hwreg(20, 0, 32)" : "=s"(xcc));  // XCC_ID
        xcc &= 7u;
        s_xcd = xcc;
        s_rank = __hip_atomic_fetch_add(&ctr[CTR_ELECT + xcc * 2 + dir], 1u,
                                        __ATOMIC_RELAXED, __HIP_MEMORY_SCOPE_AGENT);
    }

    // ================= pre-phase (before the one-time fence) =================
    const int gid = wg * 256 + tid;          // 0 .. 65535
    // (A) split x into hi/lo planes (plain stores; flushed by the one fence)
    {
        const int NG = BB * TT * EE / 8;
        for (int g = gid; g < NG; g += NWG * 256) {
            bf16x8 hi, lo;
            split8(x + (size_t)g * 8, hi, lo);
            ((bf16x8*)xhi)[g] = hi;
            ((bf16x8*)xlo)[g] = lo;
        }
    }
    // (B) zero out[0 : B*T*H)
    {
        const int NZ = BB * TT * HH / 4;
        const f32x4 z = {0.f, 0.f, 0.f, 0.f};
        for (int g = gid; g < NZ; g += NWG * 256) ((f32x4*)out)[g] = z;
    }
    // (C) tail passthrough: out[BTH : BTH+BH) = h0, then c0
    {
        float* tail = out + (size_t)BB * TT * HH;
        const int NT4 = BB * HH / 4;
        for (int g = gid; g < NT4; g += NWG * 256)
            ((f32x4*)tail)[g] = ((const f32x4*)h0)[g];
        for (int g = gid; g < NT4; g += NWG * 256)
            ((f32x4*)(tail + BB * HH))[g] = ((const f32x4*)c0)[g];
    }
    // (D) stage packed split h0 (own columns) into parity-1 hbuf (sc1 stores)
    {
        unsigned int* p1 = hbuf + ((size_t)(1 * 2 + dir)) * (BB * HH);
        for (int i = tid; i < BB * CHUNK; i += 256) {
            const int b = i >> 3, col = cb + (i & 7);
            const float v = h0[b * HH + col];
            const bf16_t vh = (bf16_t)v;
            const bf16_t vl = (bf16_t)(v - (float)vh);
            const unsigned int pk =
                (unsigned int)__builtin_bit_cast(unsigned short, vh) |
                ((unsigned int)__builtin_bit_cast(unsigned short, vl) << 16);
            __hip_atomic_store(&p1[b * HH + col], pk, __ATOMIC_RELAXED,
                               __HIP_MEMORY_SCOPE_AGENT);
        }
    }

    // ---- preload [U;W] hi/lo fragments (A operand) into registers ----
    bf16x8 whi[2][NKI], wlo[2][NKI];
    #pragma unroll
    for (int mt = 0; mt < 2; ++mt) {
        const int r    = mt * 16 + l16;                  // local row 0..31
        const int grow = (r & 3) * HH + (cb + (r >> 2)); // gate*H + hcol
        const float* urow = Uw + (size_t)grow * EE;
        const float* wrow = Ww + (size_t)grow * HH;
        #pragma unroll
        for (int ki = 0; ki < NKI; ++ki) {
            const int ws0 = (ki * 4 + wave) * 32;        // interleaved mapping
            const float* src = (ws0 < EE ? urow + ws0 : wrow + (ws0 - EE)) + quad * 8;
            split8(src, whi[mt][ki], wlo[mt][ki]);
        }
    }

    // Epilogue ownership: wave w finalizes nt == w -> batch b = wave*16 + l16.
    const int bown = wave * 16 + l16;
    float biasv[2][4];
    float cst[2];
    #pragma unroll
    for (int mt = 0; mt < 2; ++mt) {
        const int hcol = cb + mt * 4 + quad;
        #pragma unroll
        for (int g = 0; g < 4; ++g)
            biasv[mt][g] = Ub[g * HH + hcol] + Wb[g * HH + hcol];
        cst[mt] = c0[bown * HH + hcol];
    }

    // ONE-TIME fence + full-grid barrier.
    __threadfence();
    ctr_barrier(ctr + CTR_INIT, NWG);

    // Election results are final now.
    if (tid == 0)
        s_cnt = __hip_atomic_load(&ctr[CTR_ELECT + s_xcd * 2 + dir],
                                  __ATOMIC_RELAXED, __HIP_MEMORY_SCOPE_AGENT);
    __syncthreads();
    const int xcd  = (int)s_xcd;
    const int rank = (int)s_rank;
    const int cnt  = (int)s_cnt;

    const bf16_t* shi = stage + ((size_t)(xcd * 2 + dir) * 2 + 0) * PLANE_BF16;
    const bf16_t* slo = stage + ((size_t)(xcd * 2 + dir) * 2 + 1) * PLANE_BF16;
    unsigned int* xslots = ctr + CTR_XBAR + (xcd * 2 + dir) * TT;

    const f32x4 vzero = {0.f, 0.f, 0.f, 0.f};

    for (int t = 0; t < TT; ++t) {
        const int tx = dir ? (TT - 1 - t) : t;
        const int rp = (t + 1) & 1;          // read parity

        const bf16_t *xrh[4], *xrl[4];
        #pragma unroll
        for (int nt = 0; nt < 4; ++nt) {
            const int b = nt * 16 + l16;     // B-operand: n = lane&15
            const size_t xoff = ((size_t)b * TT + tx) * EE;
            xrh[nt] = xhi + xoff;  xrl[nt] = xlo + xoff;
        }

        // x fragment loads (independent of h_{t-1}; issued before the wait)
        bf16x8 xbh[NKX][4], xbl[NKX][4];
        #pragma unroll
        for (int kx = 0; kx < NKX; ++kx) {
            const int off = (kx * 4 + wave) * 32 + quad * 8;
            #pragma unroll
            for (int nt = 0; nt < 4; ++nt) {
                xbh[kx][nt] = *(const bf16x8*)(xrh[nt] + off);
                xbl[kx][nt] = *(const bf16x8*)(xrl[nt] + off);
            }
        }

        // ============ wait for h_{t-1}: distributed per-WG flags ============
        if (t > 0) {
            if (wave == 0) {
                const u64* f64 = (const u64*)flags;
                const unsigned int tgt = (unsigned int)t;
                int guard = 0;
                for (;;) {
                    const u64 v = __hip_atomic_load(f64 + lane, __ATOMIC_RELAXED,
                                                    __HIP_MEMORY_SCOPE_AGENT);
                    const int ok = ((unsigned int)v >= tgt) &&
                                   ((unsigned int)(v >> 32) >= tgt);
                    if (__all(ok)) break;
                    __builtin_amdgcn_s_sleep(1);
                    if (++guard > (1 << 22)) break;
                }
            }
            __syncthreads();
        }

        // ===== per-XCD copy: hbuf (MALL) -> stage hi/lo planes (local L2) =====
        // Fragment i: b = i>>7, k8 = i&127. Reads 32B coalesced across threads;
        // writes land in THIS XCD's L2 as plain stores (readers sc0-hit them).
        {
            const unsigned int* src = hbuf + ((size_t)(rp * 2 + dir)) * (BB * HH);
            bf16x8* dsth = (bf16x8*)shi;
            bf16x8* dstl = (bf16x8*)slo;
            for (int i = rank * 256 + tid; i < HFRAGS; i += cnt * 256) {
                const int b = i >> 7, k8 = i & 127;
                const u64* s64 = (const u64*)(src + (size_t)b * HH + k8 * 8);
                const u64 v0 = __hip_atomic_load(s64 + 0, __ATOMIC_RELAXED, __HIP_MEMORY_SCOPE_AGENT);
                const u64 v1 = __hip_atomic_load(s64 + 1, __ATOMIC_RELAXED, __HIP_MEMORY_SCOPE_AGENT);
                const u64 v2 = __hip_atomic_load(s64 + 2, __ATOMIC_RELAXED, __HIP_MEMORY_SCOPE_AGENT);
                const u64 v3 = __hip_atomic_load(s64 + 3, __ATOMIC_RELAXED, __HIP_MEMORY_SCOPE_AGENT);
                u32x4 hw, lw;
                hw[0] = __builtin_amdgcn_perm(hi32(v0), lo32(v0), 0x05040100u);
                lw[0] = __builtin_amdgcn_perm(hi32(v0), lo32(v0), 0x07060302u);
                hw[1] = __builtin_amdgcn_perm(hi32(v1), lo32(v1), 0x05040100u);
                lw[1] = __builtin_amdgcn_perm(hi32(v1), lo32(v1), 0x07060302u);
                hw[2] = __builtin_amdgcn_perm(hi32(v2), lo32(v2), 0x05040100u);
                lw[2] = __builtin_amdgcn_perm(hi32(v2), lo32(v2), 0x07060302u);
                hw[3] = __builtin_amdgcn_perm(hi32(v3), lo32(v3), 0x05040100u);
                lw[3] = __builtin_amdgcn_perm(hi32(v3), lo32(v3), 0x07060302u);
                dsth[(k8 << 6) + b] = __builtin_bit_cast(bf16x8, hw);
                dstl[(k8 << 6) + b] = __builtin_bit_cast(bf16x8, lw);
            }
        }

        // ================= x-phase MFMAs (hide copy latency) =================
        f32x4 acc[2][4];
        #pragma unroll
        for (int mt = 0; mt < 2; ++mt)
            #pragma unroll
            for (int nt = 0; nt < 4; ++nt) acc[mt][nt] = vzero;
        #pragma unroll
        for (int kx = 0; kx < NKX; ++kx)
            #pragma unroll
            for (int mt = 0; mt < 2; ++mt)
                #pragma unroll
                for (int nt = 0; nt < 4; ++nt) {
                    acc[mt][nt] = mfma_16x16x32_bf16(whi[mt][kx], xbh[kx][nt], acc[mt][nt]);
                    acc[mt][nt] = mfma_16x16x32_bf16(whi[mt][kx], xbl[kx][nt], acc[mt][nt]);
                    acc[mt][nt] = mfma_16x16x32_bf16(wlo[mt][kx], xbh[kx][nt], acc[mt][nt]);
                }

        // ====== per-(xcd,dir) barrier: copy visible in local L2 ======
        __syncthreads();                 // drains this WG's copy stores (vmcnt 0)
        if (tid == 0) {
            unsigned int* slot = xslots + t;
            __hip_atomic_fetch_add(slot, 1u, __ATOMIC_RELAXED, __HIP_MEMORY_SCOPE_AGENT);
            int guard = 0;
            while (__hip_atomic_load(slot, __ATOMIC_RELAXED, __HIP_MEMORY_SCOPE_AGENT)
                   < (unsigned int)cnt) {
                __builtin_amdgcn_s_sleep(1);
                if (++guard > (1 << 22)) break;
            }
        }
        __syncthreads();
        __builtin_amdgcn_sched_barrier(0);

        // ========== h-phase: fragment-order sc0 loads from local L2 ==========
        bf16x8 hbh[2][4], hbl[2][4];     // double-buffered fragments
        {
            const int K8 = (0 * 4 + wave) * 4;
            const bf16_t* ph = shi + ((size_t)(((K8 + quad) << 6) + l16)) * 8;
            const bf16_t* pl = slo + ((size_t)(((K8 + quad) << 6) + l16)) * 8;
            hbh[0][0] = ld_sc0<0>(ph);   hbl[0][0] = ld_sc0<0>(pl);
            hbh[0][1] = ld_sc0<256>(ph); hbl[0][1] = ld_sc0<256>(pl);
            hbh[0][2] = ld_sc0<512>(ph); hbl[0][2] = ld_sc0<512>(pl);
            hbh[0][3] = ld_sc0<768>(ph); hbl[0][3] = ld_sc0<768>(pl);
        }
        asm volatile("s_waitcnt vmcnt(0)" ::: "memory");
        __builtin_amdgcn_sched_barrier(0);
        #pragma unroll
        for (int kh = 0; kh < NKH; ++kh) {
            const int cur = kh & 1;
            if (kh + 1 < NKH) {
                const int K8 = ((kh + 1) * 4 + wave) * 4;
                const bf16_t* ph = shi + ((size_t)(((K8 + quad) << 6) + l16)) * 8;
                const bf16_t* pl = slo + ((size_t)(((K8 + quad) << 6) + l16)) * 8;
                hbh[cur ^ 1][0] = ld_sc0<0>(ph);   hbl[cur ^ 1][0] = ld_sc0<0>(pl);
                hbh[cur ^ 1][1] = ld_sc0<256>(ph); hbl[cur ^ 1][1] = ld_sc0<256>(pl);
                hbh[cur ^ 1][2] = ld_sc0<512>(ph); hbl[cur ^ 1][2] = ld_sc0<512>(pl);
                hbh[cur ^ 1][3] = ld_sc0<768>(ph); hbl[cur ^ 1][3] = ld_sc0<768>(pl);
            }
            const int ki = NKX + kh;
            #pragma unroll
            for (int mt = 0; mt < 2; ++mt)
                #pragma unroll
                for (int nt = 0; nt < 4; ++nt) {
                    acc[mt][nt] = mfma_16x16x32_bf16(whi[mt][ki], hbh[cur][nt], acc[mt][nt]);
                    acc[mt][nt] = mfma_16x16x32_bf16(whi[mt][ki], hbl[cur][nt], acc[mt][nt]);
                    acc[mt][nt] = mfma_16x16x32_bf16(wlo[mt][ki], hbh[cur][nt], acc[mt][nt]);
                }
            if (kh + 1 < NKH) {
                asm volatile("s_waitcnt vmcnt(0)" ::: "memory");
                __builtin_amdgcn_sched_barrier(0);
            }
        }

        // ================= cross-wave K reduction through LDS =================
        #pragma unroll
        for (int mt = 0; mt < 2; ++mt)
            #pragma unroll
            for (int nt = 0; nt < 4; ++nt)
                red[wave][mt * 4 + nt][lane] = acc[mt][nt];
        __syncthreads();

        unsigned int* hn32 = hbuf + ((size_t)((t & 1) * 2 + dir)) * (BB * HH);
        float hvout[2];
        #pragma unroll
        for (int mt = 0; mt < 2; ++mt) {
            const int tI = mt * 4 + wave;    // this wave finalizes nt == wave
            f32x4 s = red[0][tI][lane];
            #pragma unroll
            for (int w2 = 1; w2 < 4; ++w2) s += red[w2][tI][lane];
            const float fg = s[0] + biasv[mt][0];
            const float ig = s[1] + biasv[mt][1];
            const float gg = s[2] + biasv[mt][2];
            const float og = s[3] + biasv[mt][3];   // o gate used RAW (ref quirk)
            const float sf = 1.f / (1.f + __expf(-fg));
            const float si = 1.f / (1.f + __expf(-ig));
            float cn = cst[mt] * sf + si * tanhf(gg);
            cn = fminf(600.f, fmaxf(-600.f, cn));   // inert when correct
            cst[mt] = cn;
            float hv = og * tanhf(cn);
            hv = fminf(448.f, fmaxf(-448.f, hv));   // inert when correct
            const int hcol = cb + mt * 4 + quad;
            const bf16_t vh = (bf16_t)hv;
            const bf16_t vl = (bf16_t)(hv - (float)vh);
            const unsigned int pk =
                (unsigned int)__builtin_bit_cast(unsigned short, vh) |
                ((unsigned int)__builtin_bit_cast(unsigned short, vl) << 16);
            __hip_atomic_store(&hn32[(size_t)bown * HH + hcol], pk,
                               __ATOMIC_RELAXED, __HIP_MEMORY_SCOPE_AGENT);
            hvout[mt] = hv;
        }

        // Publish: syncthreads' implicit vmcnt(0) drains all waves' h stores
        // to the coherence point, then one flag store. out atomicAdds go AFTER
        // the flag (off the critical path).
        __syncthreads();
        if (tid == 0)
            __hip_atomic_store(&flags[wg127], (unsigned int)(t + 1),
                               __ATOMIC_RELAXED, __HIP_MEMORY_SCOPE_AGENT);
        #pragma unroll
        for (int mt = 0; mt < 2; ++mt)
            atomicAdd(&out[((size_t)bown * TT + tx) * HH + (cb + mt * 4 + quad)],
                      hvout[mt]);
    }
}

// Diagnostic sentinel: fills out with a constant so failures are attributable.
__global__ void sentinel_kernel(float* __restrict__ out, float v, size_t n)
{
    const size_t i = (size_t)blockIdx.x * blockDim.x + threadIdx.x;
    if (i < n) out[i] = v;
}

extern "C" void kernel_launch(void* const* d_in, const int* in_sizes, int n_in,
                              void* d_out, int out_size, void* d_ws, size_t ws_size,
                              hipStream_t stream)
{
    const float* x   = (const float*)d_in[0];
    const float* h0  = (const float*)d_in[1];
    const float* c0  = (const float*)d_in[2];
    const float* Ufw = (const float*)d_in[3];
    const float* Ufb = (const float*)d_in[4];
    const float* Wfw = (const float*)d_in[5];
    const float* Wfb = (const float*)d_in[6];
    const float* Ubw = (const float*)d_in[7];
    const float* Ubb = (const float*)d_in[8];
    const float* Wbw = (const float*)d_in[9];
    const float* Wbb = (const float*)d_in[10];

    const size_t n_out = (size_t)out_size;

    // ws layout: [ctr 64KB][xhi 32MB][xlo 32MB][hbuf 2MB][stage 4MB]
    const size_t XPB   = (size_t)BB * TT * EE * sizeof(bf16_t);          // 32 MiB
    const size_t HBUF  = (size_t)2 * 2 * BB * HH * sizeof(unsigned int); // 2 MiB
    const size_t STAGE = (size_t)8 * 2 * 2 * PLANE_BF16 * sizeof(bf16_t);// 4 MiB
    if (ws_size < CTRB + 2 * XPB + HBUF + STAGE) {
        hipLaunchKernelGGL(sentinel_kernel, dim3((unsigned)((n_out + 255) / 256)),
                           dim3(256), 0, stream, (float*)d_out, 1000.0f, n_out);
        return;
    }

    uint8_t* ws = (uint8_t*)d_ws;
    unsigned int* ctr = (unsigned int*)ws;
    bf16_t* xhi  = (bf16_t*)(ws + CTRB);
    bf16_t* xlo  = (bf16_t*)(ws + CTRB + XPB);
    unsigned int* hbuf = (unsigned int*)(ws + CTRB + 2 * XPB);
    bf16_t* stg  = (bf16_t*)(ws + CTRB + 2 * XPB + HBUF);
    float*  out  = (float*)d_out;

    hipMemsetAsync(ctr, 0, CTRB, stream);

    hipLaunchKernelGGL(lstm_persistent, dim3(NWG), dim3(256), 0, stream,
                       x, h0, c0, Ufw, Ufb, Wfw, Wfb, Ubw, Ubb, Wbw, Wbb,
                       xhi, xlo, hbuf, stg, out, ctr);
}

// Round 3
// 6212.010 us; speedup vs baseline: 2.0785x; 1.1275x over previous
//
#include <hip/hip_runtime.h>
#include <hip/hip_bf16.h>
#include <stdint.h>

// Problem dims
#define BB 64
#define TT 512
#define EE 512
#define HH 1024
#define CHUNK 8            // h-columns per workgroup (128 WGs per direction)
#define NKI 12             // K windows of 32 per wave (4 waves x 12 x 32 = 1536)
#define NKX 4              // x windows per wave (K 0..511)
#define NKH 8              // h windows per wave (K 512..1535)
#define NWGD 128           // workgroups per direction
#define NWG  256           // total workgroups

// ctr u32 offsets
#define CTR_INIT  0        // one-time init barrier counter
#define CTR_FLAG  16       // 256 per-WG step flags (128 per dir)
#define CTR_ELECT 512      // 16 election counters [xcd][dir]
#define CTR_XBAR  1024     // 16*512 per-step per-(xcd,dir) barrier slots
#define CTRB      65536    // bytes

#define PLANE 65536        // bf16 per plane: 128 k8 * 64 b * 8 cols

typedef __bf16 bf16_t;
typedef __bf16 bf16x8 __attribute__((ext_vector_type(8)));
typedef float  f32x4  __attribute__((ext_vector_type(4)));
typedef unsigned int u32x4 __attribute__((ext_vector_type(4)));
typedef unsigned long long u64;

static_assert(sizeof(bf16x8) == 16, "bf16x8 must be 16B");

__device__ __forceinline__ f32x4 mfma_16x16x32_bf16(bf16x8 a, bf16x8 b, f32x4 c) {
    return __builtin_amdgcn_mfma_f32_16x16x32_bf16(a, b, c, 0, 0, 0);
}

__device__ __forceinline__ unsigned int lo32(u64 v) { return (unsigned int)v; }
__device__ __forceinline__ unsigned int hi32(u64 v) { return (unsigned int)(v >> 32); }

// L1-bypassing (sc0) 16B load: hits the XCD-local L2 where the stage copier's
// plain stores landed. Untracked by compiler -> consumers use explicit counted
// s_waitcnt vmcnt(N) + sched_barrier(0) (rule #18).
template<int OFF>
__device__ __forceinline__ bf16x8 ld_sc0(const bf16_t* p) {
    bf16x8 d;
    asm volatile("global_load_dwordx4 %0, %1, off offset:%2 sc0"
                 : "=v"(d) : "v"(p), "n"(OFF));
    return d;
}

template<int N>
__device__ __forceinline__ void waitv() {
    asm volatile("s_waitcnt vmcnt(%0)" :: "i"(N) : "memory");
}

// Split 8 consecutive f32 (two float4 loads) into hi/lo bf16x8 fragments.
__device__ __forceinline__ void split8(const float* __restrict__ src,
                                       bf16x8& hi, bf16x8& lo) {
    const f32x4 a = *(const f32x4*)src;
    const f32x4 b = *(const f32x4*)(src + 4);
    #pragma unroll
    for (int j = 0; j < 4; ++j) {
        const bf16_t h0 = (bf16_t)a[j];
        hi[j] = h0;  lo[j] = (bf16_t)(a[j] - (float)h0);
        const bf16_t h1 = (bf16_t)b[j];
        hi[4 + j] = h1;  lo[4 + j] = (bf16_t)(b[j] - (float)h1);
    }
}

// One-time counter barrier (init fence only).
__device__ __forceinline__ void ctr_barrier(unsigned int* slot, unsigned int target) {
    __syncthreads();                  // drains each wave's vmem
    if (threadIdx.x == 0) {
        __hip_atomic_fetch_add(slot, 1u, __ATOMIC_RELAXED, __HIP_MEMORY_SCOPE_AGENT);
        int guard = 0;
        while (__hip_atomic_load(slot, __ATOMIC_RELAXED, __HIP_MEMORY_SCOPE_AGENT) < target) {
            __builtin_amdgcn_s_sleep(2);
            if (++guard > (1 << 22)) break;   // fail visibly, don't hang the queue
        }
    }
    __syncthreads();
}

// Persistent bidirectional LSTM, FP32 I/O, split-bf16 MFMA.
// Per step:
//   x loads (regs) -> flag wait -> pure-stream per-XCD copy of fragment-layout
//   h planes (MALL -> local L2) overlapped with x-MFMAs -> per-(xcd,dir)
//   barrier -> h-phase: 3-deep counted-vmcnt sc0 pipeline from L2 -> LDS
//   reduce -> epilogue -> LDS transpose -> dense fragment h store (agent) ->
//   drain -> flag -> out atomics.
// MFMA order identical to previous kernel => bit-identical results.
__global__ __launch_bounds__(256, 1)
void lstm_persistent(const float* __restrict__ x,
                     const float* __restrict__ h0,
                     const float* __restrict__ c0,
                     const float* __restrict__ Ufw, const float* __restrict__ Ufb,
                     const float* __restrict__ Wfw, const float* __restrict__ Wfb,
                     const float* __restrict__ Ubw, const float* __restrict__ Ubb,
                     const float* __restrict__ Wbw, const float* __restrict__ Wbb,
                     bf16_t* __restrict__ xhi,    // [B][T][E] bf16 plane
                     bf16_t* __restrict__ xlo,    // [B][T][E] bf16 plane
                     bf16_t* __restrict__ hpl,    // [parity2][dir2][pl2][PLANE] frag planes
                     bf16_t* __restrict__ stage,  // [xcd8][dir2][pl2][PLANE]
                     float*  __restrict__ out,    // [B][T][H] f32 + [2][B][H] tail
                     unsigned int* __restrict__ ctr)
{
    __shared__ f32x4 red[4][8][64];       // [wave][tile][lane] partials, 32 KiB
    __shared__ unsigned int pkbuf[4][16][8]; // [wave][b16][col8] packed (vh,vl), 2 KiB
    __shared__ unsigned int s_xcd, s_rank, s_cnt;

    const int wg   = blockIdx.x;
    const int dir  = wg >> 7;
    const int cb   = (wg & 127) * CHUNK;
    const int tid  = threadIdx.x;
    const int wave = tid >> 6;
    const int lane = tid & 63;
    const int l16  = lane & 15;
    const int quad = lane >> 4;
    const int wg127 = wg & 127;

    unsigned int* flags = ctr + CTR_FLAG + dir * NWGD;   // 128 u32 per direction

    const float* Uw = dir ? Ubw : Ufw;
    const float* Ww = dir ? Wbw : Wfw;
    const float* Ub = dir ? Ubb : Ufb;
    const float* Wb = dir ? Wbb : Wfb;

    // ---- XCD discovery + per-(xcd,dir) rank election ----
    if (tid == 0) {
        unsigned int xcc;
        asm volatile("s_getreg_b32 %0, hwreg(20, 0, 32)" : "=s"(xcc));  // XCC_ID
        xcc &= 7u;
        s_xcd = xcc;
        s_rank = __hip_atomic_fetch_add(&ctr[CTR_ELECT + xcc * 2 + dir], 1u,
                                        __ATOMIC_RELAXED, __HIP_MEMORY_SCOPE_AGENT);
    }

    // ================= pre-phase (before the one-time fence) =================
    const int gid = wg * 256 + tid;          // 0 .. 65535
    // (A) split x into hi/lo planes (plain stores; flushed by the one fence)
    {
        const int NG = BB * TT * EE / 8;
        for (int g = gid; g < NG; g += NWG * 256) {
            bf16x8 hi, lo;
            split8(x + (size_t)g * 8, hi, lo);
            ((bf16x8*)xhi)[g] = hi;
            ((bf16x8*)xlo)[g] = lo;
        }
    }
    // (B) zero out[0 : B*T*H)
    {
        const int NZ = BB * TT * HH / 4;
        const f32x4 z = {0.f, 0.f, 0.f, 0.f};
        for (int g = gid; g < NZ; g += NWG * 256) ((f32x4*)out)[g] = z;
    }
    // (C) tail passthrough: out[BTH : BTH+BH) = h0, then c0
    {
        float* tail = out + (size_t)BB * TT * HH;
        const int NT4 = BB * HH / 4;
        for (int g = gid; g < NT4; g += NWG * 256)
            ((f32x4*)tail)[g] = ((const f32x4*)h0)[g];
        for (int g = gid; g < NT4; g += NWG * 256)
            ((f32x4*)(tail + BB * HH))[g] = ((const f32x4*)c0)[g];
    }
    // (D) stage split h0 (own k8 group) into parity-1 fragment planes (agent u64)
    {
        bf16_t* p1h = hpl + ((size_t)(1 * 2 + dir) * 2 + 0) * PLANE;
        bf16_t* p1l = p1h + PLANE;
        if (tid < 128) {
            const int pl = tid >> 6, b = tid & 63;
            unsigned int d[4];
            #pragma unroll
            for (int j = 0; j < 4; ++j) {
                const float va = h0[b * HH + cb + 2 * j];
                const float vb = h0[b * HH + cb + 2 * j + 1];
                unsigned short sa, sb;
                if (pl == 0) {
                    sa = __builtin_bit_cast(unsigned short, (bf16_t)va);
                    sb = __builtin_bit_cast(unsigned short, (bf16_t)vb);
                } else {
                    sa = __builtin_bit_cast(unsigned short, (bf16_t)(va - (float)(bf16_t)va));
                    sb = __builtin_bit_cast(unsigned short, (bf16_t)(vb - (float)(bf16_t)vb));
                }
                d[j] = (unsigned int)sa | ((unsigned int)sb << 16);
            }
            u64* dst = (u64*)((pl ? p1l : p1h) + (size_t)(wg127 * 64 + b) * 8);
            __hip_atomic_store(dst + 0, (u64)d[0] | ((u64)d[1] << 32),
                               __ATOMIC_RELAXED, __HIP_MEMORY_SCOPE_AGENT);
            __hip_atomic_store(dst + 1, (u64)d[2] | ((u64)d[3] << 32),
                               __ATOMIC_RELAXED, __HIP_MEMORY_SCOPE_AGENT);
        }
    }

    // ---- preload [U;W] hi/lo fragments (A operand) into registers ----
    bf16x8 whi[2][NKI], wlo[2][NKI];
    #pragma unroll
    for (int mt = 0; mt < 2; ++mt) {
        const int r    = mt * 16 + l16;                  // local row 0..31
        const int grow = (r & 3) * HH + (cb + (r >> 2)); // gate*H + hcol
        const float* urow = Uw + (size_t)grow * EE;
        const float* wrow = Ww + (size_t)grow * HH;
        #pragma unroll
        for (int ki = 0; ki < NKI; ++ki) {
            const int ws0 = (ki * 4 + wave) * 32;        // interleaved mapping
            const float* src = (ws0 < EE ? urow + ws0 : wrow + (ws0 - EE)) + quad * 8;
            split8(src, whi[mt][ki], wlo[mt][ki]);
        }
    }

    // Epilogue ownership: wave w finalizes nt == w -> batch b = wave*16 + l16.
    const int bown = wave * 16 + l16;
    float biasv[2][4];
    float cst[2];
    #pragma unroll
    for (int mt = 0; mt < 2; ++mt) {
        const int hcol = cb + mt * 4 + quad;
        #pragma unroll
        for (int g = 0; g < 4; ++g)
            biasv[mt][g] = Ub[g * HH + hcol] + Wb[g * HH + hcol];
        cst[mt] = c0[bown * HH + hcol];
    }

    // ONE-TIME fence + full-grid barrier.
    __threadfence();
    ctr_barrier(ctr + CTR_INIT, NWG);

    // Election results are final now.
    if (tid == 0)
        s_cnt = __hip_atomic_load(&ctr[CTR_ELECT + s_xcd * 2 + dir],
                                  __ATOMIC_RELAXED, __HIP_MEMORY_SCOPE_AGENT);
    __syncthreads();
    const int xcd  = (int)s_xcd;
    const int rank = (int)s_rank;
    const int cnt  = (int)s_cnt;

    const bf16_t* shi = stage + ((size_t)(xcd * 2 + dir) * 2 + 0) * PLANE;
    const bf16_t* slo = shi + PLANE;
    unsigned int* xslots = ctr + CTR_XBAR + (xcd * 2 + dir) * TT;

    const f32x4 vzero = {0.f, 0.f, 0.f, 0.f};

    for (int t = 0; t < TT; ++t) {
        const int tx = dir ? (TT - 1 - t) : t;
        const int rp = (t + 1) & 1;          // read parity

        const bf16_t *xrh[4], *xrl[4];
        #pragma unroll
        for (int nt = 0; nt < 4; ++nt) {
            const int b = nt * 16 + l16;     // B-operand: n = lane&15
            const size_t xoff = ((size_t)b * TT + tx) * EE;
            xrh[nt] = xhi + xoff;  xrl[nt] = xlo + xoff;
        }

        // x fragment loads (independent of h_{t-1}; issued before the wait)
        bf16x8 xbh[NKX][4], xbl[NKX][4];
        #pragma unroll
        for (int kx = 0; kx < NKX; ++kx) {
            const int off = (kx * 4 + wave) * 32 + quad * 8;
            #pragma unroll
            for (int nt = 0; nt < 4; ++nt) {
                xbh[kx][nt] = *(const bf16x8*)(xrh[nt] + off);
                xbl[kx][nt] = *(const bf16x8*)(xrl[nt] + off);
            }
        }

        // ============ wait for h_{t-1}: distributed per-WG flags ============
        if (t > 0) {
            if (wave == 0) {
                const u64* f64 = (const u64*)flags;
                const unsigned int tgt = (unsigned int)t;
                int guard = 0;
                for (;;) {
                    const u64 v = __hip_atomic_load(f64 + lane, __ATOMIC_RELAXED,
                                                    __HIP_MEMORY_SCOPE_AGENT);
                    const int ok = ((unsigned int)v >= tgt) &&
                                   ((unsigned int)(v >> 32) >= tgt);
                    if (__all(ok)) break;
                    __builtin_amdgcn_s_sleep(1);
                    if (++guard > (1 << 22)) break;
                }
            }
            __syncthreads();
        }

        // ==== per-XCD pure-stream copy: hpl (MALL) -> stage (local L2) ====
        // 256 KB contiguous (hi|lo planes); fully-linear reads and writes.
        {
            const u64* s64 = (const u64*)(hpl + ((size_t)(rp * 2 + dir) * 2) * PLANE);
            u32x4* d16 = (u32x4*)(stage + ((size_t)(xcd * 2 + dir) * 2) * PLANE);
            for (int i = rank * 256 + tid; i < 16384; i += cnt * 256) {
                const u64 a = __hip_atomic_load(s64 + 2 * i,     __ATOMIC_RELAXED,
                                                __HIP_MEMORY_SCOPE_AGENT);
                const u64 b = __hip_atomic_load(s64 + 2 * i + 1, __ATOMIC_RELAXED,
                                                __HIP_MEMORY_SCOPE_AGENT);
                u32x4 v;
                v[0] = lo32(a); v[1] = hi32(a); v[2] = lo32(b); v[3] = hi32(b);
                d16[i] = v;
            }
        }

        // ================= x-phase MFMAs (hide copy latency) =================
        f32x4 acc[2][4];
        #pragma unroll
        for (int mt = 0; mt < 2; ++mt)
            #pragma unroll
            for (int nt = 0; nt < 4; ++nt) acc[mt][nt] = vzero;
        #pragma unroll
        for (int kx = 0; kx < NKX; ++kx)
            #pragma unroll
            for (int mt = 0; mt < 2; ++mt)
                #pragma unroll
                for (int nt = 0; nt < 4; ++nt) {
                    acc[mt][nt] = mfma_16x16x32_bf16(whi[mt][kx], xbh[kx][nt], acc[mt][nt]);
                    acc[mt][nt] = mfma_16x16x32_bf16(whi[mt][kx], xbl[kx][nt], acc[mt][nt]);
                    acc[mt][nt] = mfma_16x16x32_bf16(wlo[mt][kx], xbh[kx][nt], acc[mt][nt]);
                }

        // ====== per-(xcd,dir) barrier: copy visible in local L2 ======
        __syncthreads();                 // drains this WG's copy stores (vmcnt 0)
        if (tid == 0) {
            unsigned int* slot = xslots + t;
            __hip_atomic_fetch_add(slot, 1u, __ATOMIC_RELAXED, __HIP_MEMORY_SCOPE_AGENT);
            int guard = 0;
            while (__hip_atomic_load(slot, __ATOMIC_RELAXED, __HIP_MEMORY_SCOPE_AGENT)
                   < (unsigned int)cnt) {
                __builtin_amdgcn_s_sleep(1);
                if (++guard > (1 << 22)) break;
            }
        }
        __syncthreads();
        __builtin_amdgcn_sched_barrier(0);

        // == h-phase: 3-deep counted-vmcnt sc0 pipeline (8 loads/window) ==
        bf16x8 hbh[3][4], hbl[3][4];
        #define ISSUE_W(w, s)                                                   \
        {                                                                       \
            const int K8 = ((w) * 4 + wave) * 4;                                \
            const bf16_t* ph = shi + ((size_t)(((K8 + quad) << 6) + l16)) * 8;  \
            const bf16_t* pl_ = slo + ((size_t)(((K8 + quad) << 6) + l16)) * 8; \
            hbh[s][0] = ld_sc0<0>(ph);    hbh[s][1] = ld_sc0<256>(ph);          \
            hbh[s][2] = ld_sc0<512>(ph);  hbh[s][3] = ld_sc0<768>(ph);          \
            hbl[s][0] = ld_sc0<0>(pl_);   hbl[s][1] = ld_sc0<256>(pl_);         \
            hbl[s][2] = ld_sc0<512>(pl_); hbl[s][3] = ld_sc0<768>(pl_);         \
        }
        ISSUE_W(0, 0); ISSUE_W(1, 1); ISSUE_W(2, 2);
        #pragma unroll
        for (int kh = 0; kh < NKH; ++kh) {
            if (kh <= 5)      waitv<16>();   // W(kh) done; 2 newer windows in flight
            else if (kh == 6) waitv<8>();
            else              waitv<0>();
            __builtin_amdgcn_sched_barrier(0);
            const int s = kh % 3;            // static after unroll
            const int ki = NKX + kh;
            #pragma unroll
            for (int mt = 0; mt < 2; ++mt)
                #pragma unroll
                for (int nt = 0; nt < 4; ++nt) {
                    acc[mt][nt] = mfma_16x16x32_bf16(whi[mt][ki], hbh[s][nt], acc[mt][nt]);
                    acc[mt][nt] = mfma_16x16x32_bf16(whi[mt][ki], hbl[s][nt], acc[mt][nt]);
                    acc[mt][nt] = mfma_16x16x32_bf16(wlo[mt][ki], hbh[s][nt], acc[mt][nt]);
                }
            if (kh + 3 < NKH) ISSUE_W(kh + 3, s);
        }
        #undef ISSUE_W
        __builtin_amdgcn_sched_barrier(0);

        // ================= cross-wave K reduction through LDS =================
        #pragma unroll
        for (int mt = 0; mt < 2; ++mt)
            #pragma unroll
            for (int nt = 0; nt < 4; ++nt)
                red[wave][mt * 4 + nt][lane] = acc[mt][nt];
        __syncthreads();

        float hvout[2];
        #pragma unroll
        for (int mt = 0; mt < 2; ++mt) {
            const int tI = mt * 4 + wave;    // this wave finalizes nt == wave
            f32x4 s = red[0][tI][lane];
            #pragma unroll
            for (int w2 = 1; w2 < 4; ++w2) s += red[w2][tI][lane];
            const float fg = s[0] + biasv[mt][0];
            const float ig = s[1] + biasv[mt][1];
            const float gg = s[2] + biasv[mt][2];
            const float og = s[3] + biasv[mt][3];   // o gate used RAW (ref quirk)
            const float sf = 1.f / (1.f + __expf(-fg));
            const float si = 1.f / (1.f + __expf(-ig));
            float cn = cst[mt] * sf + si * tanhf(gg);
            cn = fminf(600.f, fmaxf(-600.f, cn));   // inert when correct
            cst[mt] = cn;
            float hv = og * tanhf(cn);
            hv = fminf(448.f, fmaxf(-448.f, hv));   // inert when correct
            const bf16_t vh = (bf16_t)hv;
            const bf16_t vl = (bf16_t)(hv - (float)vh);
            pkbuf[wave][l16][mt * 4 + quad] =
                (unsigned int)__builtin_bit_cast(unsigned short, vh) |
                ((unsigned int)__builtin_bit_cast(unsigned short, vl) << 16);
            hvout[mt] = hv;
        }
        __syncthreads();                     // pkbuf visible

        // ==== dense fragment store: 16 lanes/wave write 32B hi + 32B lo ====
        {
            bf16_t* dph = hpl + ((size_t)((t & 1) * 2 + dir) * 2 + 0) * PLANE;
            bf16_t* dpl = dph + PLANE;
            if (lane < 16) {
                const int b = wave * 16 + lane;
                const unsigned int* pr = &pkbuf[wave][lane][0];
                const unsigned int p0 = pr[0], p1 = pr[1], p2 = pr[2], p3 = pr[3];
                const unsigned int p4 = pr[4], p5 = pr[5], p6 = pr[6], p7 = pr[7];
                const unsigned int h0 = __builtin_amdgcn_perm(p1, p0, 0x05040100u);
                const unsigned int h1 = __builtin_amdgcn_perm(p3, p2, 0x05040100u);
                const unsigned int h2 = __builtin_amdgcn_perm(p5, p4, 0x05040100u);
                const unsigned int h3 = __builtin_amdgcn_perm(p7, p6, 0x05040100u);
                const unsigned int l0 = __builtin_amdgcn_perm(p1, p0, 0x07060302u);
                const unsigned int l1 = __builtin_amdgcn_perm(p3, p2, 0x07060302u);
                const unsigned int l2 = __builtin_amdgcn_perm(p5, p4, 0x07060302u);
                const unsigned int l3 = __builtin_amdgcn_perm(p7, p6, 0x07060302u);
                u64* dh = (u64*)(dph + (size_t)(wg127 * 64 + b) * 8);
                u64* dl = (u64*)(dpl + (size_t)(wg127 * 64 + b) * 8);
                __hip_atomic_store(dh + 0, (u64)h0 | ((u64)h1 << 32),
                                   __ATOMIC_RELAXED, __HIP_MEMORY_SCOPE_AGENT);
                __hip_atomic_store(dh + 1, (u64)h2 | ((u64)h3 << 32),
                                   __ATOMIC_RELAXED, __HIP_MEMORY_SCOPE_AGENT);
                __hip_atomic_store(dl + 0, (u64)l0 | ((u64)l1 << 32),
                                   __ATOMIC_RELAXED, __HIP_MEMORY_SCOPE_AGENT);
                __hip_atomic_store(dl + 1, (u64)l2 | ((u64)l3 << 32),
                                   __ATOMIC_RELAXED, __HIP_MEMORY_SCOPE_AGENT);
            }
        }

        // Publish: syncthreads' implicit vmcnt(0) drains all waves' h stores
        // to the coherence point, then one flag store. out atomicAdds go AFTER
        // the flag (off the critical path).
        __syncthreads();
        if (tid == 0)
            __hip_atomic_store(&flags[wg127], (unsigned int)(t + 1),
                               __ATOMIC_RELAXED, __HIP_MEMORY_SCOPE_AGENT);
        #pragma unroll
        for (int mt = 0; mt < 2; ++mt)
            atomicAdd(&out[((size_t)bown * TT + tx) * HH + (cb + mt * 4 + quad)],
                      hvout[mt]);
    }
}

// Diagnostic sentinel: fills out with a constant so failures are attributable.
__global__ void sentinel_kernel(float* __restrict__ out, float v, size_t n)
{
    const size_t i = (size_t)blockIdx.x * blockDim.x + threadIdx.x;
    if (i < n) out[i] = v;
}

extern "C" void kernel_launch(void* const* d_in, const int* in_sizes, int n_in,
                              void* d_out, int out_size, void* d_ws, size_t ws_size,
                              hipStream_t stream)
{
    const float* x   = (const float*)d_in[0];
    const float* h0  = (const float*)d_in[1];
    const float* c0  = (const float*)d_in[2];
    const float* Ufw = (const float*)d_in[3];
    const float* Ufb = (const float*)d_in[4];
    const float* Wfw = (const float*)d_in[5];
    const float* Wfb = (const float*)d_in[6];
    const float* Ubw = (const float*)d_in[7];
    const float* Ubb = (const float*)d_in[8];
    const float* Wbw = (const float*)d_in[9];
    const float* Wbb = (const float*)d_in[10];

    const size_t n_out = (size_t)out_size;

    // ws layout: [ctr 64KB][xhi 32MB][xlo 32MB][hpl 1MB][stage 4MB]
    const size_t XPB   = (size_t)BB * TT * EE * sizeof(bf16_t);          // 32 MiB
    const size_t HPLB  = (size_t)2 * 2 * 2 * PLANE * sizeof(bf16_t);     // 1 MiB
    const size_t STAGE = (size_t)8 * 2 * 2 * PLANE * sizeof(bf16_t);     // 4 MiB
    if (ws_size < CTRB + 2 * XPB + HPLB + STAGE) {
        hipLaunchKernelGGL(sentinel_kernel, dim3((unsigned)((n_out + 255) / 256)),
                           dim3(256), 0, stream, (float*)d_out, 1000.0f, n_out);
        return;
    }

    uint8_t* ws = (uint8_t*)d_ws;
    unsigned int* ctr = (unsigned int*)ws;
    bf16_t* xhi  = (bf16_t*)(ws + CTRB);
    bf16_t* xlo  = (bf16_t*)(ws + CTRB + XPB);
    bf16_t* hpl  = (bf16_t*)(ws + CTRB + 2 * XPB);
    bf16_t* stg  = (bf16_t*)(ws + CTRB + 2 * XPB + HPLB);
    float*  out  = (float*)d_out;

    hipMemsetAsync(ctr, 0, CTRB, stream);

    hipLaunchKernelGGL(lstm_persistent, dim3(NWG), dim3(256), 0, stream,
                       x, h0, c0, Ufw, Ufb, Wfw, Wfb, Ubw, Ubb, Wbw, Wbb,
                       xhi, xlo, hpl, stg, out, ctr);
}